// Round 8
// baseline (2503.644 us; speedup 1.0000x reference)
//
#include <hip/hip_runtime.h>

// ---------- problem constants ----------
#define Bz   32
#define Pz   197
#define ENCz 768
#define EMBz 512
#define HIDz 512
#define ATTz 256
#define VOCz 32000
#define Tz   40

typedef unsigned short ushort_t;
typedef __attribute__((ext_vector_type(8))) short frag_ab;     // 8 bf16 (4 VGPRs)
typedef __attribute__((ext_vector_type(4))) float frag_cd;     // 4 fp32 acc
typedef __attribute__((ext_vector_type(4))) ushort_t ushort4v; // 8B
typedef __attribute__((ext_vector_type(8))) ushort_t ushort8v; // 16B

#define MFMA16(a, b, c) __builtin_amdgcn_mfma_f32_16x16x32_bf16((a), (b), (c), 0, 0, 0)

__device__ __forceinline__ float b2f(ushort_t u) {
    return __uint_as_float(((unsigned)u) << 16);
}
__device__ __forceinline__ ushort_t f2bf(float f) {
    unsigned u = __float_as_uint(f);
    unsigned r = (u + 0x7fffu + ((u >> 16) & 1u)) >> 16;
    return (ushort_t)r;
}
__device__ __forceinline__ float sigf(float x) { return 1.f / (1.f + __expf(-x)); }
__device__ __forceinline__ float tanhfast(float x) { return 1.f - 2.f / (__expf(2.f * x) + 1.f); }

// ---------- uncached (agent-coherent) access helpers ----------
__device__ __forceinline__ void st_f32(float* p, float v) {
    __hip_atomic_store(p, v, __ATOMIC_RELAXED, __HIP_MEMORY_SCOPE_AGENT);
}
__device__ __forceinline__ float ld_f32(const float* p) {
    return __hip_atomic_load(p, __ATOMIC_RELAXED, __HIP_MEMORY_SCOPE_AGENT);
}
__device__ __forceinline__ void st_u32(unsigned* p, unsigned v) {
    __hip_atomic_store(p, v, __ATOMIC_RELAXED, __HIP_MEMORY_SCOPE_AGENT);
}
__device__ __forceinline__ unsigned ld_u32(const unsigned* p) {
    return __hip_atomic_load(p, __ATOMIC_RELAXED, __HIP_MEMORY_SCOPE_AGENT);
}
// 16B bf16 fragment via two 8B agent-scope loads (coherent, bypasses stale L2)
__device__ __forceinline__ frag_ab ldfrag(const ushort_t* p) {
    union { frag_ab f; unsigned long long q[2]; } u;
    u.q[0] = __hip_atomic_load((const unsigned long long*)p, __ATOMIC_RELAXED, __HIP_MEMORY_SCOPE_AGENT);
    u.q[1] = __hip_atomic_load((const unsigned long long*)(p + 4), __ATOMIC_RELAXED, __HIP_MEMORY_SCOPE_AGENT);
    return u.f;
}
// arrival: ensure this block's agent stores are at the coherence point, then set flag
__device__ __forceinline__ void arrive(unsigned* slot, unsigned v, int tid) {
    __syncthreads();                       // compiler drains vmcnt/lgkmcnt before s_barrier
    if (tid == 0) {
        asm volatile("s_waitcnt vmcnt(0)" ::: "memory");
        st_u32(slot, v);
    }
}

__global__ void k_binit(unsigned* f) {
    for (int i = threadIdx.x; i < 1024; i += 256) f[i] = 0u;
}

// ---------- fused prep: bf16 convert (blocks 0..2363), mean (2364..2459), encTb (2460..7835) ----------
__global__ __launch_bounds__(256) void k_prep(const float* __restrict__ enc, ushort_t* __restrict__ encB,
                                              float* __restrict__ meanE, ushort_t* __restrict__ encTb) {
    __shared__ float tile[32][33];
    const int bid = blockIdx.x, tid = threadIdx.x;
    if (bid < 2364) {
        size_t base = ((size_t)bid * 256 + tid) * 8;
        const float4* src = (const float4*)(enc + base);
        float4 a = src[0], b = src[1];
        ushort8v v;
        v[0] = f2bf(a.x); v[1] = f2bf(a.y); v[2] = f2bf(a.z); v[3] = f2bf(a.w);
        v[4] = f2bf(b.x); v[5] = f2bf(b.y); v[6] = f2bf(b.z); v[7] = f2bf(b.w);
        *(ushort8v*)(encB + base) = v;
    } else if (bid < 2460) {
        int e = (bid - 2364) * 256 + tid;
        int b = e / ENCz, d = e % ENCz;
        const float* p = enc + (size_t)b * Pz * ENCz + d;
        float s = 0.f;
        for (int i = 0; i < Pz; ++i) s += p[i * ENCz];
        meanE[e] = s * (1.f / (float)Pz);
    } else {
        int idx = bid - 2460;
        int d0 = (idx % 24) * 32; int rest = idx / 24;
        int p0 = (rest % 7) * 32; int b = rest / 7;
        int tx = tid & 31, ty = tid >> 5;
#pragma unroll
        for (int i = 0; i < 4; ++i) {
            int p = p0 + ty + i * 8;
            tile[ty + i * 8][tx] = (p < Pz) ? enc[((size_t)b * Pz + p) * ENCz + d0 + tx] : 0.f;
        }
        __syncthreads();
#pragma unroll
        for (int i = 0; i < 4; ++i) {
            int d = d0 + ty + i * 8, p = p0 + tx;
            if (p < 200) encTb[((size_t)b * ENCz + d) * 200 + p] = f2bf(tile[tx][ty + i * 8]);
        }
    }
}

// ---------- h0/c0 init (h0 bf16 -> hbuf) ----------
__global__ __launch_bounds__(256) void k_h0c0(const float* __restrict__ meanE,
                                              const float* __restrict__ W_inh, const float* __restrict__ b_inh,
                                              const float* __restrict__ W_inc, const float* __restrict__ b_inc,
                                              float* __restrict__ c_cur, ushort_t* __restrict__ hbuf) {
    __shared__ float msh[ENCz];
    int bid = blockIdx.x, tid = threadIdx.x;
    int b = bid >> 2, seg = bid & 3;             // seg0/1: h halves, seg2/3: c halves
    for (int i = tid; i < ENCz; i += 256) msh[i] = meanE[b * ENCz + i];
    __syncthreads();
    int col = (seg & 1) * 256 + tid;
    bool isc = (seg >> 1) != 0;
    const float* W = isc ? W_inc : W_inh;
    const float* bb = isc ? b_inc : b_inh;
    float a0 = 0.f, a1 = 0.f, a2 = 0.f, a3 = 0.f;
    for (int k = 0; k < ENCz; k += 4) {
        a0 += msh[k + 0] * W[(k + 0) * HIDz + col];
        a1 += msh[k + 1] * W[(k + 1) * HIDz + col];
        a2 += msh[k + 2] * W[(k + 2) * HIDz + col];
        a3 += msh[k + 3] * W[(k + 3) * HIDz + col];
    }
    float acc = a0 + a1 + a2 + a3 + bb[col];
    if (isc) c_cur[b * HIDz + col] = acc;
    else hbuf[b * HIDz + col] = f2bf(acc);
}

// ---------- embedding gather+convert ----------
__global__ __launch_bounds__(128) void k_gather(const int* __restrict__ captions, const float* __restrict__ emb,
                                                ushort_t* __restrict__ Xemb) {
    int row = blockIdx.x;                        // 0..1279 = t*32+b
    int t = row >> 5, b = row & 31;
    int cap = captions[b * 41 + t];
    float4 f = *(const float4*)(emb + (size_t)cap * EMBz + threadIdx.x * 4);
    ushort4v v; v[0] = f2bf(f.x); v[1] = f2bf(f.y); v[2] = f2bf(f.z); v[3] = f2bf(f.w);
    *(ushort4v*)(Xemb + (size_t)row * EMBz + threadIdx.x * 4) = v;
}

// ---------- fp32-in / bf16-out transpose ----------
__global__ __launch_bounds__(256) void k_transpose(const float* __restrict__ in, int R, int C,
                                                   ushort_t* __restrict__ out, int ldo, int koff) {
    __shared__ ushort_t tile[32][33];
    int c0 = blockIdx.x * 32, r0 = blockIdx.y * 32;
    int tx = threadIdx.x & 31, ty = threadIdx.x >> 5;    // ty 0..7
#pragma unroll
    for (int i = 0; i < 4; ++i) {
        int r = r0 + ty + i * 8;
        tile[ty + i * 8][tx] = f2bf(in[(size_t)r * C + c0 + tx]);
    }
    __syncthreads();
#pragma unroll
    for (int i = 0; i < 4; ++i) {
        int c = c0 + ty + i * 8;
        out[(size_t)c * ldo + koff + r0 + tx] = tile[tx][ty + i * 8];
    }
}

// ---------- MFMA GEMM ----------
// MODE 0: fp32 out (ldo), bias1+bias2;  MODE 1: bf16 out (ldo), bias1, row-guard
// MODE 2: fp32 out permuted for final preds (row m=t*32+b -> out[b][t][n]), XCD-swizzled grid
template <int MODE>
__global__ __launch_bounds__(256) void k_gemm(const ushort_t* __restrict__ A, int lda, int M,
                                              const ushort_t* __restrict__ BT, int K,
                                              const float* __restrict__ B1, const float* __restrict__ B2,
                                              void* __restrict__ out, int ldo) {
    __shared__ __align__(16) ushort_t As[128 * 64];
    __shared__ __align__(16) ushort_t Bs[128 * 64];
    const int tid = threadIdx.x;
    const int lane = tid & 63, w = tid >> 6;
    const int wm = w >> 1, wn = w & 1;
    int n0, m0;
    if (MODE == 2) {
        const int total = gridDim.x * gridDim.y;
        const int lin = blockIdx.y * gridDim.x + blockIdx.x;
        const int q = total >> 3, r = total - (q << 3);
        const int xcd = lin & 7, slot = lin >> 3;
        const int L = (xcd < r) ? xcd * (q + 1) + slot : r * (q + 1) + (xcd - r) * q + slot;
        const int nIdx = L / (int)gridDim.y;
        n0 = nIdx * 128; m0 = (L - nIdx * (int)gridDim.y) * 128;
    } else {
        n0 = blockIdx.x * 128; m0 = blockIdx.y * 128;
    }
    const int quad = lane >> 4, c16 = lane & 15;

    frag_cd acc[4][4];
#pragma unroll
    for (int i = 0; i < 4; ++i)
#pragma unroll
        for (int j = 0; j < 4; ++j) acc[i][j] = (frag_cd){0.f, 0.f, 0.f, 0.f};

    for (int k0 = 0; k0 < K; k0 += 64) {
#pragma unroll
        for (int it = 0; it < 4; ++it) {
            int c = tid + it * 256;              // chunk 0..1023
            int row = c >> 3, col8 = (c & 7) * 8;
            int gr = m0 + row; gr = gr < M ? gr : M - 1;
            *(frag_ab*)&As[row * 64 + col8] = *(const frag_ab*)&A[(size_t)gr * lda + k0 + col8];
            *(frag_ab*)&Bs[row * 64 + col8] = *(const frag_ab*)&BT[(size_t)(n0 + row) * K + k0 + col8];
        }
        __syncthreads();
#pragma unroll
        for (int kk = 0; kk < 64; kk += 32) {
            int kcol = kk + quad * 8;
            frag_ab af[4], bf[4];
#pragma unroll
            for (int i = 0; i < 4; ++i) af[i] = *(const frag_ab*)&As[(wm * 64 + i * 16 + c16) * 64 + kcol];
#pragma unroll
            for (int j = 0; j < 4; ++j) bf[j] = *(const frag_ab*)&Bs[(wn * 64 + j * 16 + c16) * 64 + kcol];
#pragma unroll
            for (int i = 0; i < 4; ++i)
#pragma unroll
                for (int j = 0; j < 4; ++j) acc[i][j] = MFMA16(af[i], bf[j], acc[i][j]);
        }
        __syncthreads();
    }

#pragma unroll
    for (int i = 0; i < 4; ++i) {
#pragma unroll
        for (int j = 0; j < 4; ++j) {
            int n = n0 + wn * 64 + j * 16 + c16;
            float bias = B1[n];
            if (B2 != nullptr) bias += B2[n];
#pragma unroll
            for (int r = 0; r < 4; ++r) {
                int m = m0 + wm * 64 + i * 16 + quad * 4 + r;
                float v = acc[i][j][r] + bias;
                if (MODE == 0) {
                    if (m < M) ((float*)out)[(size_t)m * ldo + n] = v;
                } else if (MODE == 1) {
                    if (m < M) ((ushort_t*)out)[(size_t)m * ldo + n] = f2bf(v);
                } else {
                    int b = m & 31, t = m >> 5;
                    ((float*)out)[(size_t)b * (Tz * VOCz) + (size_t)t * VOCz + n] = v;
                }
            }
        }
    }
}

// ---------- persistent recurrence: 32 blocks x 1024 threads, 3 hops/step, 32-way fan-in ----------
// A: pre = h(32x512) @ W_pre cols [g*32,+32) via m=32 MFMA (4 waves) -> pre_buf (bias/sigmoid applied)
// B: batch g: e (att1 LDS) + softmax + awe (encTb from L2) + gate-mul -> gawe_buf bf16
// C: gates cols {q*512+g*16+j}: m=32 MFMA (A-frags agent from gawe|h), 2-way K-split + LSTM -> hbuf
__global__ __launch_bounds__(1024, 1) void k_recur(
    const ushort_t* __restrict__ att1, const ushort_t* __restrict__ encTb,
    const ushort_t* __restrict__ W_preT, const float* __restrict__ b_da,
    const float* __restrict__ b_fb, const float* __restrict__ w_fa,
    const float* __restrict__ b_fa, const ushort_t* __restrict__ WgT,
    const float* __restrict__ Xih, const float* __restrict__ c0,
    float* __restrict__ pre_buf, ushort_t* __restrict__ gawe_buf,
    ushort_t* __restrict__ hbuf, ushort_t* __restrict__ Hall,
    unsigned* __restrict__ flags)
{
    __shared__ __align__(16) ushort_t att1L[197 * 264];        // 104,016 B
    __shared__ float wfa_sh[256];
    __shared__ float att2_sh[256];
    __shared__ float gate_sh[768];
    __shared__ float alpha_sh[200];
    __shared__ float g4[2][4][32][16];                         // [khalf][q][m][j] 16 KB
    __shared__ float red[16];

    const int g = (int)blockIdx.x;
    const int tid = (int)threadIdx.x;
    const int lane = tid & 63, wv = tid >> 6;
    const int quad = lane >> 4, c16 = lane & 15;

    // ---- one-time staging ----
    for (int i = 0; i < 7; ++i) {
        int c = tid + i * 1024;
        if (c < 6304) {
            int p = c >> 5, off = (c & 31) * 8;
            *(ushort8v*)&att1L[p * 264 + off] =
                *(const ushort8v*)&att1[((size_t)(g * Pz + p)) * 256 + off];
        }
    }
    if (tid < 256) wfa_sh[tid] = w_fa[tid];
    float creg = 0.f;
    if (tid < 512) creg = c0[(tid >> 4) * HIDz + g * 16 + (tid & 15)];
    const float bfa = b_fa[0];
    __syncthreads();

    for (int t = 0; t < Tz; ++t) {
        // ============ A: pre-GEMM (att2|gate cols g*32..+31) ============
        if (t) {
            if (tid < 32) while (ld_u32(&flags[tid << 5]) < (unsigned)(3 * t)) __builtin_amdgcn_s_sleep(2);
            __syncthreads();
        }
        if (wv < 4) {
            const int mt = wv >> 1, nt = wv & 1;
            frag_cd acc = (frag_cd){0.f, 0.f, 0.f, 0.f};
            const ushort_t* hrow = hbuf + (size_t)(mt * 16 + c16) * HIDz;
            const ushort_t* wrow = W_preT + (size_t)(g * 32 + nt * 16 + c16) * HIDz;
#pragma unroll
            for (int kk = 0; kk < 512; kk += 32) {
                frag_ab af = ldfrag(hrow + kk + quad * 8);
                frag_ab bf = *(const frag_ab*)&wrow[kk + quad * 8];
                acc = MFMA16(af, bf, acc);
            }
            const int n = g * 32 + nt * 16 + c16;
            const float bias = (n < 256) ? b_da[n] : b_fb[n - 256];
#pragma unroll
            for (int r = 0; r < 4; ++r) {
                int m = mt * 16 + quad * 4 + r;
                float v = acc[r] + bias;
                if (n >= 256) v = sigf(v);
                st_f32(&pre_buf[m * 1024 + n], v);
            }
        }
        arrive(&flags[g << 5], (unsigned)(3 * t + 1), tid);

        // ============ B: e + softmax + awe (batch g) ============
        if (tid < 32) while (ld_u32(&flags[tid << 5]) < (unsigned)(3 * t + 1)) __builtin_amdgcn_s_sleep(2);
        __syncthreads();
        if (tid < 256) att2_sh[tid] = ld_f32(&pre_buf[g * 1024 + tid]);
        else gate_sh[tid - 256] = ld_f32(&pre_buf[g * 1024 + tid]);
        __syncthreads();
        float ev = -3.0e38f;
        if (tid < Pz) {
            const ushort_t* ar = att1L + tid * 264;
            float s = 0.f;
#pragma unroll
            for (int j8 = 0; j8 < 256; j8 += 8) {
                ushort8v v = *(const ushort8v*)&ar[j8];
#pragma unroll
                for (int jj = 0; jj < 8; ++jj)
                    s += fmaxf(b2f(v[jj]) + att2_sh[j8 + jj], 0.f) * wfa_sh[j8 + jj];
            }
            ev = s + bfa;
        }
        float mv = ev;
        for (int o = 32; o; o >>= 1) mv = fmaxf(mv, __shfl_down(mv, o, 64));
        if (lane == 0 && wv < 4) red[wv] = mv;
        __syncthreads();
        const float mx = fmaxf(fmaxf(red[0], red[1]), fmaxf(red[2], red[3]));
        float ex = (tid < Pz) ? __expf(ev - mx) : 0.f;
        float sv = ex;
        for (int o = 32; o; o >>= 1) sv += __shfl_down(sv, o, 64);
        if (lane == 0 && wv < 4) red[4 + wv] = sv;
        __syncthreads();
        const float inv = 1.f / (red[4] + red[5] + red[6] + red[7]);
        if (tid < 200) alpha_sh[tid] = (tid < Pz) ? ex * inv : 0.f;
        __syncthreads();
        if (tid < 768) {
            const ushort_t* er = encTb + ((size_t)(g * ENCz + tid)) * 200;
            float s = 0.f;
#pragma unroll
            for (int c = 0; c < 25; ++c) {
                ushort8v v = *(const ushort8v*)&er[c * 8];
#pragma unroll
                for (int jj = 0; jj < 8; ++jj) s += b2f(v[jj]) * alpha_sh[c * 8 + jj];
            }
            float gs = s * gate_sh[tid];
            unsigned pk = f2bf(gs);
            unsigned nb = __shfl_down(pk, 1, 64);
            if ((tid & 1) == 0) st_u32((unsigned*)&gawe_buf[g * 768 + tid], pk | (nb << 16));
        }
        arrive(&flags[g << 5], (unsigned)(3 * t + 2), tid);

        // ============ C: gates MFMA (cols q*512+g*16+j) + LSTM ============
        if (tid < 32) while (ld_u32(&flags[tid << 5]) < (unsigned)(3 * t + 2)) __builtin_amdgcn_s_sleep(2);
        __syncthreads();
        {
            const int kh = wv & 1, q = (wv >> 1) & 3, mt = wv >> 3;
            frag_cd acc = (frag_cd){0.f, 0.f, 0.f, 0.f};
            const int jcol = q * 512 + g * 16 + c16;
            const ushort_t* wrow = WgT + (size_t)jcol * 1280;
            const int arow = mt * 16 + c16;
            const ushort_t* grow = gawe_buf + (size_t)arow * 768;
            const ushort_t* hrow = hbuf + (size_t)arow * 512;
#pragma unroll
            for (int ki = 0; ki < 20; ++ki) {
                const int k = kh * 640 + ki * 32;
                frag_ab af = (k < 768) ? ldfrag(grow + k + quad * 8)
                                       : ldfrag(hrow + (k - 768) + quad * 8);
                frag_ab bf = *(const frag_ab*)&wrow[k + quad * 8];
                acc = MFMA16(af, bf, acc);
            }
#pragma unroll
            for (int r = 0; r < 4; ++r)
                g4[kh][q][mt * 16 + quad * 4 + r][c16] = acc[r];
        }
        __syncthreads();
        if (tid < 512) {
            const int m = tid >> 4, jj = tid & 15;
            const float* xr = Xih + (size_t)t * 65536 + m * 2048 + g * 16 + jj;
            const float iv = g4[0][0][m][jj] + g4[1][0][m][jj] + xr[0];
            const float fv = g4[0][1][m][jj] + g4[1][1][m][jj] + xr[512];
            const float gv = g4[0][2][m][jj] + g4[1][2][m][jj] + xr[1024];
            const float ov = g4[0][3][m][jj] + g4[1][3][m][jj] + xr[1536];
            const float cn = sigf(fv) * creg + sigf(iv) * tanhfast(gv);
            creg = cn;
            const float hn = sigf(ov) * tanhfast(cn);
            const ushort_t hb = f2bf(hn);
            Hall[((size_t)t * 32 + m) * HIDz + g * 16 + jj] = hb;
            unsigned pk = hb;
            unsigned nb = __shfl_down(pk, 1, 64);
            if ((tid & 1) == 0)
                st_u32((unsigned*)&hbuf[m * 512 + g * 16 + jj], pk | (nb << 16));
        }
        arrive(&flags[g << 5], (unsigned)(3 * t + 3), tid);
    }
}

// ---------- launcher ----------
extern "C" void kernel_launch(void* const* d_in, const int* in_sizes, int n_in,
                              void* d_out, int out_size, void* d_ws, size_t ws_size,
                              hipStream_t stream) {
    const float* enc   = (const float*)d_in[0];
    const int*   caps  = (const int*)d_in[1];
    const float* emb   = (const float*)d_in[2];
    const float* W_ea  = (const float*)d_in[3];
    const float* b_ea  = (const float*)d_in[4];
    const float* W_da  = (const float*)d_in[5];
    const float* b_da  = (const float*)d_in[6];
    const float* w_fa  = (const float*)d_in[7];
    const float* b_fa  = (const float*)d_in[8];
    const float* W_inh = (const float*)d_in[9];
    const float* b_inh = (const float*)d_in[10];
    const float* W_inc = (const float*)d_in[11];
    const float* b_inc = (const float*)d_in[12];
    const float* W_fb  = (const float*)d_in[13];
    const float* b_fb  = (const float*)d_in[14];
    const float* W_ih  = (const float*)d_in[15];
    const float* b_ih  = (const float*)d_in[16];
    const float* W_hh  = (const float*)d_in[17];
    const float* b_hh  = (const float*)d_in[18];
    const float* W_out = (const float*)d_in[19];
    const float* b_out = (const float*)d_in[20];

    char* ws = (char*)d_ws;
    ushort_t* att1     = (ushort_t*)(ws + 0);            // 6304x256 bf16     -> 3,227,648
    ushort_t* Xemb     = (ushort_t*)(ws + 3227648);      // 1280x512 bf16     -> 4,538,368
    ushort_t* encB     = (ushort_t*)(ws + 4538368);      // 6304x768 bf16     -> 14,221,312
    float*    Xih      = (float*)(ws + 14221312);        // 40x32x2048 fp32   -> 24,707,072
    float*    meanE    = (float*)(ws + 24707072);        // 32x768 fp32       -> 24,805,376
    float*    c_cur    = (float*)(ws + 24805376);        // 32x512 fp32       -> 24,870,912
    float*    pre_buf  = (float*)(ws + 24870912);        // 32x1024 fp32      -> 25,001,984
    ushort_t* gawe_buf = (ushort_t*)(ws + 25001984);     // 32x768 bf16       -> 25,051,136
    ushort_t* hbuf     = (ushort_t*)(ws + 25051136);     // 32x512 bf16       -> 25,083,904
    unsigned* flags    = (unsigned*)(ws + 25083904);     // 1024 u32          -> 25,088,000
    ushort_t* Hall     = (ushort_t*)(ws + 25191424);     // 1280x512 bf16     -> 26,502,144
    ushort_t* WgT      = (ushort_t*)(ws + 26502144);     // 2048x1280 bf16    -> 31,745,024
    ushort_t* W_preT   = (ushort_t*)(ws + 31745024);     // 1024x512 bf16     -> 32,793,600
    ushort_t* W_eaT    = (ushort_t*)(ws + 32793600);     // 256x768 bf16      -> 33,186,816
    ushort_t* W_ihxT   = (ushort_t*)(ws + 33186816);     // 2048x512 bf16     -> 35,283,968
    ushort_t* W_outT   = (ushort_t*)(ws + 35283968);     // 32000x512 bf16    -> 68,051,968
    ushort_t* encTb    = (ushort_t*)(ws + 68051968);     // 32x768x200 bf16   -> 77,882,368

    // precompute (order-independent, single stream)
    k_binit<<<1, 256, 0, stream>>>(flags);
    k_prep<<<7836, 256, 0, stream>>>(enc, encB, meanE, encTb);
    k_h0c0<<<128, 256, 0, stream>>>(meanE, W_inh, b_inh, W_inc, b_inc, c_cur, hbuf);
    k_gather<<<1280, 128, 0, stream>>>(caps, emb, Xemb);
    k_transpose<<<dim3(8, 24), 256, 0, stream>>>(W_ea, 768, 256, W_eaT, 768, 0);
    k_transpose<<<dim3(64, 16), 256, 0, stream>>>(W_ih, 512, 2048, W_ihxT, 512, 0);
    k_transpose<<<dim3(64, 24), 256, 0, stream>>>(W_ih + 512 * 2048, 768, 2048, WgT, 1280, 0);
    k_transpose<<<dim3(64, 16), 256, 0, stream>>>(W_hh, 512, 2048, WgT, 1280, 768);
    k_transpose<<<dim3(8, 16), 256, 0, stream>>>(W_da, 512, 256, W_preT, 512, 0);
    k_transpose<<<dim3(24, 16), 256, 0, stream>>>(W_fb, 512, 768, W_preT + 256 * 512, 512, 0);
    k_transpose<<<dim3(1000, 16), 256, 0, stream>>>(W_out, 512, 32000, W_outT, 512, 0);

    // att1 = enc @ W_ea + b_ea   (bf16 out, row-major [b*197+p][256])
    k_gemm<1><<<dim3(2, 50), 256, 0, stream>>>(encB, 768, 6304, W_eaT, 768, b_ea, nullptr, att1, 256);
    // Xih = Xemb @ W_ih[:512] + b_ih + b_hh  (fp32 out)
    k_gemm<0><<<dim3(16, 10), 256, 0, stream>>>(Xemb, 512, 1280, W_ihxT, 512, b_ih, b_hh, Xih, 2048);

    // full 40-step recurrence: 32 blocks x 1024 threads, 3 hops/step with 32-way fan-in
    hipLaunchKernelGGL(k_recur, dim3(32), dim3(1024), 0, stream,
                       att1, encTb, W_preT, b_da, b_fb, w_fa, b_fa, WgT, Xih,
                       c_cur, pre_buf, gawe_buf, hbuf, Hall, flags);

    // preds = Hall @ W_out + b_out -> d_out (B,T,V) fp32
    k_gemm<2><<<dim3(250, 10), 256, 0, stream>>>(Hall, 512, 1280, W_outT, 512, b_out, nullptr, d_out, VOCz);
}